// Round 10
// baseline (860.422 us; speedup 1.0000x reference)
//
#include <hip/hip_runtime.h>
#include <hip/hip_bf16.h>

#define DEV __device__ __forceinline__

typedef __attribute__((ext_vector_type(4))) float f32x4;
typedef __attribute__((ext_vector_type(8))) __bf16 bf16v;
typedef __attribute__((ext_vector_type(8))) unsigned short u16x8;
typedef __attribute__((ext_vector_type(4))) unsigned short u16x4;

DEV unsigned short f2b(float x) {
    unsigned u = __builtin_bit_cast(unsigned, x);
    unsigned r = u + 0x7FFF + ((u >> 16) & 1);
    return (unsigned short)(r >> 16);
}
DEV float b2f(unsigned short u) {
    unsigned v = (unsigned)u << 16;
    return __builtin_bit_cast(float, v);
}

DEV void gl_lds16(const void* g, void* l) {
    __builtin_amdgcn_global_load_lds(
        (const __attribute__((address_space(1))) unsigned*)g,
        (__attribute__((address_space(3))) unsigned*)l,
        16, 0, 0);
}

// ---------------- fused preprocessing (1 kernel) ----------------

DEV void transp_dev(const float* __restrict__ in, unsigned short* __restrict__ out,
                    int R, int C, int bx, int by, float (*t)[33]) {
    int tx = threadIdx.x & 31, ty = threadIdx.x >> 5;
    long c0 = (long)bx * 32, r0 = (long)by * 32;
#pragma unroll
    for (int i = 0; i < 4; i++)
        t[ty + i * 8][tx] = in[(r0 + ty + i * 8) * C + c0 + tx];
    __syncthreads();
#pragma unroll
    for (int i = 0; i < 4; i++)
        out[(c0 + ty + i * 8) * R + r0 + tx] = f2b(t[tx][ty + i * 8]);
}

__global__ __launch_bounds__(256) void prep_all(
    const float* __restrict__ x, const float* __restrict__ wq,
    const float* __restrict__ wk, const float* __restrict__ wv,
    const float* __restrict__ wo, const float* __restrict__ w1,
    const float* __restrict__ w2, const float* __restrict__ bq,
    const float* __restrict__ bk, const float* __restrict__ bv,
    unsigned short* __restrict__ xb, unsigned short* __restrict__ wqkvT,
    unsigned short* __restrict__ woT, unsigned short* __restrict__ w1T,
    unsigned short* __restrict__ w2T, float* __restrict__ bqkv) {
    __shared__ float t[32][33];
    int id = blockIdx.x;
    if (id < 8192) {
        long i = ((long)id * 256 + threadIdx.x) * 4;
        float4 f = *(const float4*)(x + i);
        u16x4 u;
        u[0] = f2b(f.x); u[1] = f2b(f.y); u[2] = f2b(f.z); u[3] = f2b(f.w);
        *(u16x4*)(xb + i) = u;
        return;
    }
    id -= 8192;
    if (id < 1024) { transp_dev(wq, wqkvT, 1024, 1024, id & 31, id >> 5, t); return; }
    id -= 1024;
    if (id < 1024) { transp_dev(wk, wqkvT + 1048576, 1024, 1024, id & 31, id >> 5, t); return; }
    id -= 1024;
    if (id < 1024) { transp_dev(wv, wqkvT + 2097152, 1024, 1024, id & 31, id >> 5, t); return; }
    id -= 1024;
    if (id < 1024) { transp_dev(wo, woT, 1024, 1024, id & 31, id >> 5, t); return; }
    id -= 1024;
    if (id < 4096) { transp_dev(w1, w1T, 1024, 4096, id & 127, id >> 7, t); return; }
    id -= 4096;
    if (id < 4096) { transp_dev(w2, w2T, 4096, 1024, id & 31, id >> 5, t); return; }
    id -= 4096;
    int i = id * 256 + threadIdx.x;
    float v = (i < 1024) ? bq[i] : (i < 2048) ? bk[i - 1024] : bv[i - 2048];
    bqkv[i] = v;
}

DEV float waveSum(float v) {
#pragma unroll
    for (int o = 32; o > 0; o >>= 1) v += __shfl_xor(v, o);
    return v;
}

__global__ __launch_bounds__(256) void ln_rows(const float* __restrict__ in,
                                               const float* __restrict__ g,
                                               const float* __restrict__ b,
                                               float* __restrict__ outF,
                                               unsigned short* __restrict__ outB) {
    const float* p = in + (long)blockIdx.x * 1024;
    __shared__ float red[4], red2[4];
    int t = threadIdx.x, lane = t & 63, wave = t >> 6;
    float4 v = ((const float4*)p)[t];
    float s = v.x + v.y + v.z + v.w;
    float q = v.x * v.x + v.y * v.y + v.z * v.z + v.w * v.w;
    s = waveSum(s); q = waveSum(q);
    if (lane == 0) { red[wave] = s; red2[wave] = q; }
    __syncthreads();
    s = red[0] + red[1] + red[2] + red[3];
    q = red2[0] + red2[1] + red2[2] + red2[3];
    float mean = s * (1.0f / 1024.0f);
    float var = q * (1.0f / 1024.0f) - mean * mean;
    float rstd = rsqrtf(var + 1e-10f);
    float4 gg = ((const float4*)g)[t];
    float4 bb = ((const float4*)b)[t];
    float4 o;
    o.x = gg.x * ((v.x - mean) * rstd) + bb.x;
    o.y = gg.y * ((v.y - mean) * rstd) + bb.y;
    o.z = gg.z * ((v.z - mean) * rstd) + bb.z;
    o.w = gg.w * ((v.w - mean) * rstd) + bb.w;
    if (outF) ((float4*)(outF + (long)blockIdx.x * 1024))[t] = o;
    if (outB) {
        u16x4 u;
        u[0] = f2b(o.x); u[1] = f2b(o.y); u[2] = f2b(o.z); u[3] = f2b(o.w);
        *(u16x4*)(outB + (long)blockIdx.x * 1024 + (long)t * 4) = u;
    }
}

// ---------------- fused attention (32 q-rows/block, 8 waves) ----------------
// grid 4096 (64 row-blocks x 64 z), block 512.
// Waves: wg = w>>2 (row-group of 16), wj = w&3 (512-col slice).
// K staged once per block (shared by both row-groups) -> halves K/V L2 traffic.
// P bf16 lives in 128 KB LDS (reuses dead K region) for the PV step.
__global__ __launch_bounds__(512, 1) void attn_fused(
    const unsigned short* __restrict__ qb,   // [z][2048][64] bf16
    const unsigned short* __restrict__ kb,   // [z][2048][64] bf16
    const unsigned short* __restrict__ vt,   // [z][64][2048] bf16
    float* __restrict__ attn,                // [z][2048][2048] fp32
    unsigned short* __restrict__ ao) {       // [tok][1024] bf16
    __shared__ __align__(16) char smem[131072];   // K dbuf [0,64K); later P 32x4KB
    __shared__ float sredM[8][16], sredS[8][16];

    int id = blockIdx.x;
    int swz = (id & 7) * 512 + (id >> 3);    // XCD-aware: 4096 % 8 == 0
    const int z = swz >> 6;
    const int m0 = (swz & 63) * 32;

    const int tid = threadIdx.x, lane = tid & 63, w = tid >> 6;
    const int wg = w >> 2, wj = w & 3;
    const int g = lane >> 4, l15 = lane & 15;

    const char* qz = (const char*)(qb + (long)z * 131072);
    const char* kz = (const char*)(kb + (long)z * 131072);
    const char* vz = (const char*)(vt + (long)z * 131072);

    // Q A-frags for this wave's 16 rows
    const char* qrow = qz + (long)(m0 + wg * 16 + l15) * 128;
    bf16v aq0 = *(const bf16v*)(qrow + g * 16);
    bf16v aq1 = *(const bf16v*)(qrow + 64 + g * 16);

    f32x4 acc[8][4];
#pragma unroll
    for (int c = 0; c < 8; c++)
#pragma unroll
        for (int t = 0; t < 4; t++) acc[c][t] = (f32x4)(0.0f);

    // pre-swizzled source offset: row&7 == (lane>>3)&7 for every staged row
    const int soff = ((lane & 7) * 16) ^ (((lane >> 3) & 7) << 4);

    // stage K chunk c (256 rows, 32 KB) with all 8 waves: 4 loads/thread
    auto stage = [&](int c) {
        const char* src = kz + (long)(c * 256 + w * 8 + (lane >> 3)) * 128 + soff;
        char* dst = smem + (c & 1) * 32768 + w * 1024;
#pragma unroll
        for (int i = 0; i < 4; ++i)
            gl_lds16(src + (long)i * 8192, dst + i * 8192);
    };

    stage(0);
    for (int c = 0; c < 8; ++c) {
        if (c < 7) {
            stage(c + 1);
            asm volatile("s_waitcnt vmcnt(4)" ::: "memory");
        } else {
            asm volatile("s_waitcnt vmcnt(0)" ::: "memory");
        }
        __builtin_amdgcn_sched_barrier(0);
        __builtin_amdgcn_s_barrier();   // chunk c landed for all waves
        const char* base = smem + (c & 1) * 32768;
#pragma unroll
        for (int t = 0; t < 4; ++t) {
            const int row = wj * 64 + t * 16 + l15;
            const char* bp = base + row * 128;
            const int sw = (lane & 7) << 4;
            bf16v bk0 = *(const bf16v*)(bp + ((g * 16) ^ sw));
            bf16v bk1 = *(const bf16v*)(bp + ((64 + g * 16) ^ sw));
            acc[c][t] = __builtin_amdgcn_mfma_f32_16x16x32_bf16(aq0, bk0, acc[c][t], 0, 0, 0);
            acc[c][t] = __builtin_amdgcn_mfma_f32_16x16x32_bf16(aq1, bk1, acc[c][t], 0, 0, 0);
        }
        __builtin_amdgcn_s_barrier();   // done reading half (c&1) before overwrite
    }

    // ---- softmax: rows of group wg, cols split across 4 wj-waves ----
    float M[4], S[4];
#pragma unroll
    for (int j = 0; j < 4; ++j) {
        float m = -1e30f;
#pragma unroll
        for (int c = 0; c < 8; c++)
#pragma unroll
            for (int t = 0; t < 4; t++) m = fmaxf(m, acc[c][t][j]);
        m = fmaxf(m, __shfl_xor(m, 1));
        m = fmaxf(m, __shfl_xor(m, 2));
        m = fmaxf(m, __shfl_xor(m, 4));
        m = fmaxf(m, __shfl_xor(m, 8));
        M[j] = m;
    }
    if (l15 == 0) {
        sredM[w][g * 4 + 0] = M[0];
        sredM[w][g * 4 + 1] = M[1];
        sredM[w][g * 4 + 2] = M[2];
        sredM[w][g * 4 + 3] = M[3];
    }
    __syncthreads();
#pragma unroll
    for (int j = 0; j < 4; ++j) {
        int r = g * 4 + j;
        M[j] = 0.125f * fmaxf(fmaxf(sredM[wg * 4 + 0][r], sredM[wg * 4 + 1][r]),
                              fmaxf(sredM[wg * 4 + 2][r], sredM[wg * 4 + 3][r]));
        S[j] = 0.0f;
    }
#pragma unroll
    for (int c = 0; c < 8; c++)
#pragma unroll
        for (int t = 0; t < 4; t++) {
            f32x4 v = acc[c][t];
            v[0] = __expf(v[0] * 0.125f - M[0]);
            v[1] = __expf(v[1] * 0.125f - M[1]);
            v[2] = __expf(v[2] * 0.125f - M[2]);
            v[3] = __expf(v[3] * 0.125f - M[3]);
            acc[c][t] = v;
            S[0] += v[0]; S[1] += v[1]; S[2] += v[2]; S[3] += v[3];
        }
#pragma unroll
    for (int j = 0; j < 4; ++j) {
        float s = S[j];
        s += __shfl_xor(s, 1);
        s += __shfl_xor(s, 2);
        s += __shfl_xor(s, 4);
        s += __shfl_xor(s, 8);
        S[j] = s;
    }
    if (l15 == 0) {
        sredS[w][g * 4 + 0] = S[0];
        sredS[w][g * 4 + 1] = S[1];
        sredS[w][g * 4 + 2] = S[2];
        sredS[w][g * 4 + 3] = S[3];
    }
    __syncthreads();   // also: all waves past QK^T -> K region reusable for P
    float inv[4];
#pragma unroll
    for (int j = 0; j < 4; ++j) {
        int r = g * 4 + j;
        inv[j] = 1.0f / (sredS[wg * 4 + 0][r] + sredS[wg * 4 + 1][r] +
                         sredS[wg * 4 + 2][r] + sredS[wg * 4 + 3][r]);
    }

    // ---- write P: fp32 -> d_out, bf16 -> LDS (32 rows x 4096 B, swizzled) ----
    float* ab = attn + (long)z * 4194304 + (long)(m0 + wg * 16) * 2048;
#pragma unroll
    for (int c = 0; c < 8; c++)
#pragma unroll
        for (int t = 0; t < 4; t++) {
            const int col = c * 256 + wj * 64 + t * 16 + l15;
#pragma unroll
            for (int j = 0; j < 4; ++j) {
                const int r = g * 4 + j;
                const int pr = wg * 16 + r;
                float p = acc[c][t][j] * inv[j];
                ab[(long)r * 2048 + col] = p;
                *(unsigned short*)(smem + pr * 4096 + ((col * 2) ^ ((pr & 7) << 4))) = f2b(p);
            }
        }
    __syncthreads();

    // ---- PV: wave (wg,wj) -> out rows wg*16.., d-slice wj*16.. ----
    f32x4 o0 = (f32x4)(0.0f), o1 = (f32x4)(0.0f);
    f32x4 o2 = (f32x4)(0.0f), o3 = (f32x4)(0.0f);
    const char* vtile = vz + (long)(wj * 16 + l15) * 4096;
    const char* prow = smem + (long)(wg * 16 + l15) * 4096;
    const int psw = (l15 & 7) << 4;
#pragma unroll 4
    for (int ks = 0; ks < 64; ks += 4) {
        bf16v pa0 = *(const bf16v*)(prow + (((ks + 0) * 64 + g * 16) ^ psw));
        bf16v pa1 = *(const bf16v*)(prow + (((ks + 1) * 64 + g * 16) ^ psw));
        bf16v pa2 = *(const bf16v*)(prow + (((ks + 2) * 64 + g * 16) ^ psw));
        bf16v pa3 = *(const bf16v*)(prow + (((ks + 3) * 64 + g * 16) ^ psw));
        bf16v bv0 = *(const bf16v*)(vtile + (ks + 0) * 64 + g * 16);
        bf16v bv1 = *(const bf16v*)(vtile + (ks + 1) * 64 + g * 16);
        bf16v bv2 = *(const bf16v*)(vtile + (ks + 2) * 64 + g * 16);
        bf16v bv3 = *(const bf16v*)(vtile + (ks + 3) * 64 + g * 16);
        o0 = __builtin_amdgcn_mfma_f32_16x16x32_bf16(pa0, bv0, o0, 0, 0, 0);
        o1 = __builtin_amdgcn_mfma_f32_16x16x32_bf16(pa1, bv1, o1, 0, 0, 0);
        o2 = __builtin_amdgcn_mfma_f32_16x16x32_bf16(pa2, bv2, o2, 0, 0, 0);
        o3 = __builtin_amdgcn_mfma_f32_16x16x32_bf16(pa3, bv3, o3, 0, 0, 0);
    }
    o0 = o0 + o1 + o2 + o3;

    const int b = z >> 4, h = z & 15;
    const long tokbase = (long)b * 2048 + m0 + wg * 16 + g * 4;
#pragma unroll
    for (int j = 0; j < 4; ++j)
        ao[(tokbase + j) * 1024 + h * 64 + wj * 16 + l15] = f2b(o0[j]);
}

// ---------------- GEMM modes / args ----------------

enum { M_QKV3 = 0, M_RES = 1, M_RESB = 2, M_RELU = 3 };

struct GArgs {
    const unsigned short* A;
    long lda;
    const unsigned short* B;
    long ldb;
    const float* bias;
    const float* resid;            // fp32 residual (M_RES)
    const unsigned short* residB;  // bf16 residual (M_RESB)
    float* outF;
    unsigned short* outB;    // q (QKV3) / bf16 out
    unsigned short* outB2;   // k (QKV3)
    unsigned short* outB3;   // vt (QKV3)
    long ldo;
    int K;
};

// ---------------- 256x256 counted-vmcnt pipelined GEMM (8 waves) ----------------
template <int MODE>
__global__ __launch_bounds__(512, 1) void gemm256(GArgs g) {
    __shared__ __align__(16) char smem[131072];
    const int tid = threadIdx.x, lane = tid & 63, wave = tid >> 6;
    const int wr = wave >> 2, wc = wave & 3;
    const int g2 = lane >> 4, l15 = lane & 15;
    const long m0 = (long)blockIdx.x * 256, n0 = (long)blockIdx.y * 256;
    const char* Ab = (const char*)(g.A + m0 * g.lda);
    const char* Bb = (const char*)(g.B + n0 * g.ldb);
    const long lda2 = g.lda * 2, ldb2 = g.ldb * 2;

    f32x4 acc[8][4];
#pragma unroll
    for (int mi = 0; mi < 8; mi++)
#pragma unroll
        for (int ni = 0; ni < 4; ni++) acc[mi][ni] = (f32x4)(0.0f);

    auto stage = [&](int t) {
        const int buf = (t & 1) * 32768;
        const long k0b = (long)t * 128;
#pragma unroll
        for (int i = 0; i < 4; ++i) {
            int c = i * 8 + wave;
            int p = c * 1024 + lane * 16;
            int row = p >> 7;
            int scb = (p & 127) ^ ((row & 7) << 4);
            gl_lds16(Ab + (long)row * lda2 + k0b + scb, smem + buf + c * 1024);
        }
#pragma unroll
        for (int i = 0; i < 4; ++i) {
            int c = i * 8 + wave;
            int p = c * 1024 + lane * 16;
            int row = p >> 7;
            int scb = (p & 127) ^ ((row & 7) << 4);
            gl_lds16(Bb + (long)row * ldb2 + k0b + scb, smem + 65536 + buf + c * 1024);
        }
    };

    const int NT = g.K >> 6;
    stage(0);
    for (int t = 0; t < NT; ++t) {
        if (t + 1 < NT) {
            stage(t + 1);
            asm volatile("s_waitcnt vmcnt(8)" ::: "memory");
        } else {
            asm volatile("s_waitcnt vmcnt(0)" ::: "memory");
        }
        __builtin_amdgcn_sched_barrier(0);
        __builtin_amdgcn_s_barrier();
        const char* bufA = smem + (t & 1) * 32768;
        const char* bufB = smem + 65536 + (t & 1) * 32768;
        bf16v bfr[4][2];
#pragma unroll
        for (int ni = 0; ni < 4; ++ni) {
            int r = wc * 64 + ni * 16 + l15;
            const char* bp = bufB + r * 128;
            int sw = (r & 7) << 4;
            bfr[ni][0] = *(const bf16v*)(bp + ((g2 * 16) ^ sw));
            bfr[ni][1] = *(const bf16v*)(bp + ((64 + g2 * 16) ^ sw));
        }
#pragma unroll
        for (int q = 0; q < 4; ++q) {
            bf16v af[2][2];
#pragma unroll
            for (int u = 0; u < 2; ++u) {
                int r = wr * 128 + (q * 2 + u) * 16 + l15;
                const char* ap = bufA + r * 128;
                int sw = (r & 7) << 4;
                af[u][0] = *(const bf16v*)(ap + ((g2 * 16) ^ sw));
                af[u][1] = *(const bf16v*)(ap + ((64 + g2 * 16) ^ sw));
            }
            asm volatile("s_waitcnt lgkmcnt(0)" ::: "memory");
            __builtin_amdgcn_sched_barrier(0);
            __builtin_amdgcn_s_setprio(1);
#pragma unroll
            for (int u = 0; u < 2; ++u)
#pragma unroll
                for (int ni = 0; ni < 4; ++ni) {
                    acc[q * 2 + u][ni] = __builtin_amdgcn_mfma_f32_16x16x32_bf16(
                        af[u][0], bfr[ni][0], acc[q * 2 + u][ni], 0, 0, 0);
                    acc[q * 2 + u][ni] = __builtin_amdgcn_mfma_f32_16x16x32_bf16(
                        af[u][1], bfr[ni][1], acc[q * 2 + u][ni], 0, 0, 0);
                }
            __builtin_amdgcn_s_setprio(0);
        }
        __builtin_amdgcn_sched_barrier(0);
        __builtin_amdgcn_s_barrier();
    }

#pragma unroll
    for (int mi = 0; mi < 8; mi++)
#pragma unroll
        for (int ni = 0; ni < 4; ni++) {
            if constexpr (MODE == M_QKV3) {
                long r = m0 + wr * 128 + mi * 16 + g2 * 4;
                long c = n0 + wc * 64 + ni * 16 + l15;
                long b = r >> 11, s = r & 2047;
                float bi = g.bias[c];
                if (c < 2048) {
                    unsigned short* dst = (c < 1024) ? g.outB : g.outB2;
                    long h = (c >> 6) & 15, d = c & 63;
                    long base = ((b * 16 + h) * 2048 + s) * 64 + d;
#pragma unroll
                    for (int j = 0; j < 4; ++j)
                        dst[base + (long)j * 64] = f2b(acc[mi][ni][j] + bi);
                } else {
                    long h = (c - 2048) >> 6, d = c & 63;
                    u16x4 u;
#pragma unroll
                    for (int j = 0; j < 4; ++j) u[j] = f2b(acc[mi][ni][j] + bi);
                    *(u16x4*)(g.outB3 + (b * 16 + h) * 131072 + d * 2048 + s) = u;
                }
            } else {  // M_RELU
#pragma unroll
                for (int j = 0; j < 4; ++j) {
                    long r = m0 + wr * 128 + mi * 16 + g2 * 4 + j;
                    long c = n0 + wc * 64 + ni * 16 + l15;
                    float tv = acc[mi][ni][j] + g.bias[c];
                    g.outB[r * g.ldo + c] = f2b(tv > 0.0f ? tv : 0.0f);
                }
            }
        }
}

// ---------------- 256x128 counted-vmcnt pipelined GEMM (8 waves, 2-deep) ----------
template <int MODE>
__global__ __launch_bounds__(512, 1) void gemm256x128(GArgs g) {
    __shared__ __align__(16) char smem[98304];
    const int tid = threadIdx.x, lane = tid & 63, wave = tid >> 6;
    const int wr = wave >> 1, wc = wave & 1;
    const int g2 = lane >> 4, l15 = lane & 15;
    const long m0 = (long)blockIdx.x * 256, n0 = (long)blockIdx.y * 128;
    const char* Ab = (const char*)(g.A + m0 * g.lda);
    const char* Bb = (const char*)(g.B + n0 * g.ldb);
    const long lda2 = g.lda * 2, ldb2 = g.ldb * 2;

    f32x4 acc[4][4];
#pragma unroll
    for (int mi = 0; mi < 4; mi++)
#pragma unroll
        for (int ni = 0; ni < 4; ni++) acc[mi][ni] = (f32x4)(0.0f);

    auto stage = [&](int t) {
        const int bufA = (t & 1) * 32768;
        const int bufB = 65536 + (t & 1) * 16384;
        const long k0b = (long)t * 128;
#pragma unroll
        for (int i = 0; i < 4; ++i) {
            int c = i * 8 + wave;
            int p = c * 1024 + lane * 16;
            int row = p >> 7;
            int scb = (p & 127) ^ ((row & 7) << 4);
            gl_lds16(Ab + (long)row * lda2 + k0b + scb, smem + bufA + c * 1024);
        }
#pragma unroll
        for (int i = 0; i < 2; ++i) {
            int c = i * 8 + wave;
            int p = c * 1024 + lane * 16;
            int row = p >> 7;
            int scb = (p & 127) ^ ((row & 7) << 4);
            gl_lds16(Bb + (long)row * ldb2 + k0b + scb, smem + bufB + c * 1024);
        }
    };

    const int NT = g.K >> 6;
    stage(0);
    for (int t = 0; t < NT; ++t) {
        if (t + 1 < NT) {
            stage(t + 1);
            asm volatile("s_waitcnt vmcnt(6)" ::: "memory");
        } else {
            asm volatile("s_waitcnt vmcnt(0)" ::: "memory");
        }
        __builtin_amdgcn_sched_barrier(0);
        __builtin_amdgcn_s_barrier();
        const char* bufA = smem + (t & 1) * 32768;
        const char* bufB = smem + 65536 + (t & 1) * 16384;
        bf16v bfr[4][2];
#pragma unroll
        for (int ni = 0; ni < 4; ++ni) {
            int r = wc * 64 + ni * 16 + l15;
            const char* bp = bufB + r * 128;
            int sw = (r & 7) << 4;
            bfr[ni][0] = *(const bf16v*)(bp + ((g2 * 16) ^ sw));
            bfr[ni][1] = *(const bf16v*)(bp + ((64 + g2 * 16) ^ sw));
        }
#pragma unroll
        for (int q = 0; q < 4; ++q) {
            bf16v af0, af1;
            {
                int r = wr * 64 + q * 16 + l15;
                const char* ap = bufA + r * 128;
                int sw = (r & 7) << 4;
                af0 = *(const bf16v*)(ap + ((g2 * 16) ^ sw));
                af1 = *(const bf16v*)(ap + ((64 + g2 * 16) ^ sw));
            }
            asm volatile("s_waitcnt lgkmcnt(0)" ::: "memory");
            __builtin_amdgcn_sched_barrier(0);
            __builtin_amdgcn_s_setprio(1);
#pragma unroll
            for (int ni = 0; ni < 4; ++ni) {
                acc[q][ni] = __builtin_amdgcn_mfma_f32_16x16x32_bf16(
                    af0, bfr[ni][0], acc[q][ni], 0, 0, 0);
                acc[q][ni] = __builtin_amdgcn_mfma_f32_16x16x32_bf16(
                    af1, bfr[ni][1], acc[q][ni], 0, 0, 0);
            }
            __builtin_amdgcn_s_setprio(0);
        }
        __builtin_amdgcn_sched_barrier(0);
        __builtin_amdgcn_s_barrier();
    }

#pragma unroll
    for (int mi = 0; mi < 4; mi++)
#pragma unroll
        for (int ni = 0; ni < 4; ni++)
#pragma unroll
            for (int j = 0; j < 4; ++j) {
                long r = m0 + wr * 64 + mi * 16 + g2 * 4 + j;
                long c = n0 + wc * 64 + ni * 16 + l15;
                float v = acc[mi][ni][j] + g.bias[c];
                long i = r * g.ldo + c;
                if constexpr (MODE == M_RES) {
                    g.outF[i] = v + g.resid[i];
                } else {  // M_RESB
                    g.outF[i] = v + b2f(g.residB[i]);
                }
            }
}

// ---------------- host ----------------

extern "C" void kernel_launch(void* const* d_in, const int* in_sizes, int n_in,
                              void* d_out, int out_size, void* d_ws, size_t ws_size,
                              hipStream_t stream) {
    const float* x = (const float*)d_in[0];
    const float* wq = (const float*)d_in[1];
    const float* bq = (const float*)d_in[2];
    const float* wk = (const float*)d_in[3];
    const float* bk = (const float*)d_in[4];
    const float* wv = (const float*)d_in[5];
    const float* bv = (const float*)d_in[6];
    const float* wo = (const float*)d_in[7];
    const float* bo = (const float*)d_in[8];
    const float* g1 = (const float*)d_in[9];
    const float* b1 = (const float*)d_in[10];
    const float* w1 = (const float*)d_in[11];
    const float* bf1 = (const float*)d_in[12];
    const float* w2 = (const float*)d_in[13];
    const float* bf2 = (const float*)d_in[14];
    const float* g2 = (const float*)d_in[15];
    const float* b2 = (const float*)d_in[16];

    float* out2 = (float*)d_out;
    float* attn = (float*)d_out + 8388608;

    char* ws = (char*)d_ws;
    size_t off = 0;
    auto alc = [&](size_t bytes) { size_t r = off; off += (bytes + 255) & ~(size_t)255; return r; };

    unsigned short* xb    = (unsigned short*)(ws + alc(16777216));
    unsigned short* wqkvT = (unsigned short*)(ws + alc(6291456));   // [3072][1024]
    unsigned short* woT   = (unsigned short*)(ws + alc(2097152));
    unsigned short* w1T   = (unsigned short*)(ws + alc(8388608));
    unsigned short* w2T   = (unsigned short*)(ws + alc(8388608));
    float* bqkv           = (float*)(ws + alc(12288));
    size_t bigOff = alc(67108864);           // q,k,vt block; later reused by ff1
    unsigned short* qb = (unsigned short*)(ws + bigOff);
    unsigned short* kb = qb + 8388608;
    unsigned short* vt = kb + 8388608;
    unsigned short* ff1 = qb;                // alias (q/k/vt dead by FFN1)
    size_t aoOff = alc(16777216);            // attn_out bf16; later out1 bf16
    unsigned short* ao  = (unsigned short*)(ws + aoOff);
    unsigned short* o1b = ao;                // alias
    size_t rOff = alc(33554432);             // resid1; later resid2
    float* r1 = (float*)(ws + rOff);
    float* r2 = r1;                          // alias

    // 1. fused preprocessing: x->bf16, all weight transposes, bias pack
    prep_all<<<20492, 256, 0, stream>>>(x, wq, wk, wv, wo, w1, w2, bq, bk, bv,
                                        xb, wqkvT, woT, w1T, w2T, bqkv);

    // 2. fused QKV (256x256 pipelined): Q,K -> [b,h,s,d]; V -> V^T [b,h,d,s]
    {
        GArgs a{};
        a.A = xb; a.lda = 1024; a.B = wqkvT; a.ldb = 1024; a.K = 1024;
        a.bias = bqkv; a.outB = qb; a.outB2 = kb; a.outB3 = vt;
        gemm256<M_QKV3><<<dim3(32, 12), 512, 0, stream>>>(a);
    }
    // 3. fused scores+softmax+PV (32 rows/block): writes attn (d_out) + ao
    attn_fused<<<4096, 512, 0, stream>>>(qb, kb, vt, attn, ao);
    // 4. out-proj + bias + residual(x) -> r1 fp32 (256x128 pipelined)
    {
        GArgs a{};
        a.A = ao; a.lda = 1024; a.B = woT; a.ldb = 1024;
        a.bias = bo; a.resid = x; a.outF = r1; a.ldo = 1024; a.K = 1024;
        gemm256x128<M_RES><<<dim3(32, 8), 512, 0, stream>>>(a);
    }
    // 5. LN1 -> o1b bf16 only
    ln_rows<<<8192, 256, 0, stream>>>(r1, g1, b1, nullptr, o1b);
    // 6. FFN1 + ReLU (256x256 pipelined) -> ff1 bf16
    {
        GArgs a{};
        a.A = o1b; a.lda = 1024; a.B = w1T; a.ldb = 1024;
        a.bias = bf1; a.outB = ff1; a.ldo = 4096; a.K = 1024;
        gemm256<M_RELU><<<dim3(32, 16), 512, 0, stream>>>(a);
    }
    // 7. FFN2 + bias + residual(o1b bf16) -> r2 fp32 (256x128 pipelined, K=4096)
    {
        GArgs a{};
        a.A = ff1; a.lda = 4096; a.B = w2T; a.ldb = 4096;
        a.bias = bf2; a.residB = o1b; a.outF = r2; a.ldo = 1024; a.K = 4096;
        gemm256x128<M_RESB><<<dim3(32, 8), 512, 0, stream>>>(a);
    }
    // 8. LN2 -> out2 (d_out)
    ln_rows<<<8192, 256, 0, stream>>>(r2, g2, b2, out2, nullptr);

    (void)in_sizes; (void)n_in; (void)out_size; (void)ws_size;
}

// Round 11
// 799.158 us; speedup vs baseline: 1.0767x; 1.0767x over previous
//
#include <hip/hip_runtime.h>
#include <hip/hip_bf16.h>

#define DEV __device__ __forceinline__

typedef __attribute__((ext_vector_type(4))) float f32x4;
typedef __attribute__((ext_vector_type(8))) __bf16 bf16v;
typedef __attribute__((ext_vector_type(8))) unsigned short u16x8;
typedef __attribute__((ext_vector_type(4))) unsigned short u16x4;

DEV unsigned short f2b(float x) {
    unsigned u = __builtin_bit_cast(unsigned, x);
    unsigned r = u + 0x7FFF + ((u >> 16) & 1);
    return (unsigned short)(r >> 16);
}
DEV float b2f(unsigned short u) {
    unsigned v = (unsigned)u << 16;
    return __builtin_bit_cast(float, v);
}

DEV void gl_lds16(const void* g, void* l) {
    __builtin_amdgcn_global_load_lds(
        (const __attribute__((address_space(1))) unsigned*)g,
        (__attribute__((address_space(3))) unsigned*)l,
        16, 0, 0);
}

// ---------------- fused preprocessing (1 kernel) ----------------

DEV void transp_dev(const float* __restrict__ in, unsigned short* __restrict__ out,
                    int R, int C, int bx, int by, float (*t)[33]) {
    int tx = threadIdx.x & 31, ty = threadIdx.x >> 5;
    long c0 = (long)bx * 32, r0 = (long)by * 32;
#pragma unroll
    for (int i = 0; i < 4; i++)
        t[ty + i * 8][tx] = in[(r0 + ty + i * 8) * C + c0 + tx];
    __syncthreads();
#pragma unroll
    for (int i = 0; i < 4; i++)
        out[(c0 + ty + i * 8) * R + r0 + tx] = f2b(t[tx][ty + i * 8]);
}

__global__ __launch_bounds__(256) void prep_all(
    const float* __restrict__ x, const float* __restrict__ wq,
    const float* __restrict__ wk, const float* __restrict__ wv,
    const float* __restrict__ wo, const float* __restrict__ w1,
    const float* __restrict__ w2, const float* __restrict__ bq,
    const float* __restrict__ bk, const float* __restrict__ bv,
    unsigned short* __restrict__ xb, unsigned short* __restrict__ wqkvT,
    unsigned short* __restrict__ woT, unsigned short* __restrict__ w1T,
    unsigned short* __restrict__ w2T, float* __restrict__ bqkv) {
    __shared__ float t[32][33];
    int id = blockIdx.x;
    if (id < 8192) {
        long i = ((long)id * 256 + threadIdx.x) * 4;
        float4 f = *(const float4*)(x + i);
        u16x4 u;
        u[0] = f2b(f.x); u[1] = f2b(f.y); u[2] = f2b(f.z); u[3] = f2b(f.w);
        *(u16x4*)(xb + i) = u;
        return;
    }
    id -= 8192;
    if (id < 1024) { transp_dev(wq, wqkvT, 1024, 1024, id & 31, id >> 5, t); return; }
    id -= 1024;
    if (id < 1024) { transp_dev(wk, wqkvT + 1048576, 1024, 1024, id & 31, id >> 5, t); return; }
    id -= 1024;
    if (id < 1024) { transp_dev(wv, wqkvT + 2097152, 1024, 1024, id & 31, id >> 5, t); return; }
    id -= 1024;
    if (id < 1024) { transp_dev(wo, woT, 1024, 1024, id & 31, id >> 5, t); return; }
    id -= 1024;
    if (id < 4096) { transp_dev(w1, w1T, 1024, 4096, id & 127, id >> 7, t); return; }
    id -= 4096;
    if (id < 4096) { transp_dev(w2, w2T, 4096, 1024, id & 31, id >> 5, t); return; }
    id -= 4096;
    int i = id * 256 + threadIdx.x;
    float v = (i < 1024) ? bq[i] : (i < 2048) ? bk[i - 1024] : bv[i - 2048];
    bqkv[i] = v;
}

DEV float waveSum(float v) {
#pragma unroll
    for (int o = 32; o > 0; o >>= 1) v += __shfl_xor(v, o);
    return v;
}

__global__ __launch_bounds__(256) void ln_rows(const float* __restrict__ in,
                                               const float* __restrict__ g,
                                               const float* __restrict__ b,
                                               float* __restrict__ outF,
                                               unsigned short* __restrict__ outB) {
    const float* p = in + (long)blockIdx.x * 1024;
    __shared__ float red[4], red2[4];
    int t = threadIdx.x, lane = t & 63, wave = t >> 6;
    float4 v = ((const float4*)p)[t];
    float s = v.x + v.y + v.z + v.w;
    float q = v.x * v.x + v.y * v.y + v.z * v.z + v.w * v.w;
    s = waveSum(s); q = waveSum(q);
    if (lane == 0) { red[wave] = s; red2[wave] = q; }
    __syncthreads();
    s = red[0] + red[1] + red[2] + red[3];
    q = red2[0] + red2[1] + red2[2] + red2[3];
    float mean = s * (1.0f / 1024.0f);
    float var = q * (1.0f / 1024.0f) - mean * mean;
    float rstd = rsqrtf(var + 1e-10f);
    float4 gg = ((const float4*)g)[t];
    float4 bb = ((const float4*)b)[t];
    float4 o;
    o.x = gg.x * ((v.x - mean) * rstd) + bb.x;
    o.y = gg.y * ((v.y - mean) * rstd) + bb.y;
    o.z = gg.z * ((v.z - mean) * rstd) + bb.z;
    o.w = gg.w * ((v.w - mean) * rstd) + bb.w;
    if (outF) ((float4*)(outF + (long)blockIdx.x * 1024))[t] = o;
    if (outB) {
        u16x4 u;
        u[0] = f2b(o.x); u[1] = f2b(o.y); u[2] = f2b(o.z); u[3] = f2b(o.w);
        *(u16x4*)(outB + (long)blockIdx.x * 1024 + (long)t * 4) = u;
    }
}

// ---------------- fused attention (round-8 verified: 16 rows, 4 waves, 2 blk/CU) ----
__global__ __launch_bounds__(256, 2) void attn_fused(
    const unsigned short* __restrict__ qb,   // [z][2048][64] bf16
    const unsigned short* __restrict__ kb,   // [z][2048][64] bf16
    const unsigned short* __restrict__ vt,   // [z][64][2048] bf16
    float* __restrict__ attn,                // [z][2048][2048] fp32
    unsigned short* __restrict__ ao) {       // [tok][1024] bf16
    __shared__ __align__(16) char smem[65536];
    __shared__ float sredM[4][16], sredS[4][16];

    int id = blockIdx.x;
    int swz = (id & 7) * 1024 + (id >> 3);
    const int z = swz >> 7;
    const int m0 = (swz & 127) * 16;

    const int tid = threadIdx.x, lane = tid & 63, w = tid >> 6;
    const int g = lane >> 4, l15 = lane & 15;

    const char* qz = (const char*)(qb + (long)z * 131072);
    const char* kz = (const char*)(kb + (long)z * 131072);
    const char* vz = (const char*)(vt + (long)z * 131072);

    const char* qrow = qz + (long)(m0 + l15) * 128;
    bf16v aq0 = *(const bf16v*)(qrow + g * 16);
    bf16v aq1 = *(const bf16v*)(qrow + 64 + g * 16);

    f32x4 acc[8][4];
#pragma unroll
    for (int c = 0; c < 8; c++)
#pragma unroll
        for (int t = 0; t < 4; t++) acc[c][t] = (f32x4)(0.0f);

    const int soff = ((lane & 7) * 16) ^ (((lane >> 3) & 7) << 4);

    auto stage = [&](int c) {
        const char* src = kz + (long)(c * 256 + w * 8 + (lane >> 3)) * 128 + soff;
        char* dst = smem + (c & 1) * 32768 + w * 1024;
#pragma unroll
        for (int i = 0; i < 8; ++i)
            gl_lds16(src + (long)i * 4096, dst + i * 4096);
    };

    stage(0);
    for (int c = 0; c < 8; ++c) {
        if (c < 7) {
            stage(c + 1);
            asm volatile("s_waitcnt vmcnt(8)" ::: "memory");
        } else {
            asm volatile("s_waitcnt vmcnt(0)" ::: "memory");
        }
        __builtin_amdgcn_sched_barrier(0);
        __builtin_amdgcn_s_barrier();   // all waves' chunk-c loads landed
        const char* base = smem + (c & 1) * 32768;
#pragma unroll
        for (int t = 0; t < 4; ++t) {
            const int row = w * 64 + t * 16 + l15;
            const char* bp = base + row * 128;
            const int sw = (lane & 7) << 4;
            bf16v bk0 = *(const bf16v*)(bp + ((g * 16) ^ sw));
            bf16v bk1 = *(const bf16v*)(bp + ((64 + g * 16) ^ sw));
            acc[c][t] = __builtin_amdgcn_mfma_f32_16x16x32_bf16(aq0, bk0, acc[c][t], 0, 0, 0);
            acc[c][t] = __builtin_amdgcn_mfma_f32_16x16x32_bf16(aq1, bk1, acc[c][t], 0, 0, 0);
        }
        __builtin_amdgcn_s_barrier();   // done reading half (c&1) before overwrite
    }

    // ---- softmax over full rows ----
    float M[4], S[4];
#pragma unroll
    for (int j = 0; j < 4; ++j) {
        float m = -1e30f;
#pragma unroll
        for (int c = 0; c < 8; c++)
#pragma unroll
            for (int t = 0; t < 4; t++) m = fmaxf(m, acc[c][t][j]);
        m = fmaxf(m, __shfl_xor(m, 1));
        m = fmaxf(m, __shfl_xor(m, 2));
        m = fmaxf(m, __shfl_xor(m, 4));
        m = fmaxf(m, __shfl_xor(m, 8));
        M[j] = m;
    }
    if (l15 == 0) {
        sredM[w][g * 4 + 0] = M[0];
        sredM[w][g * 4 + 1] = M[1];
        sredM[w][g * 4 + 2] = M[2];
        sredM[w][g * 4 + 3] = M[3];
    }
    __syncthreads();
#pragma unroll
    for (int j = 0; j < 4; ++j) {
        int r = g * 4 + j;
        M[j] = 0.125f * fmaxf(fmaxf(sredM[0][r], sredM[1][r]),
                              fmaxf(sredM[2][r], sredM[3][r]));
        S[j] = 0.0f;
    }
#pragma unroll
    for (int c = 0; c < 8; c++)
#pragma unroll
        for (int t = 0; t < 4; t++) {
            f32x4 v = acc[c][t];
            v[0] = __expf(v[0] * 0.125f - M[0]);
            v[1] = __expf(v[1] * 0.125f - M[1]);
            v[2] = __expf(v[2] * 0.125f - M[2]);
            v[3] = __expf(v[3] * 0.125f - M[3]);
            acc[c][t] = v;
            S[0] += v[0]; S[1] += v[1]; S[2] += v[2]; S[3] += v[3];
        }
#pragma unroll
    for (int j = 0; j < 4; ++j) {
        float s = S[j];
        s += __shfl_xor(s, 1);
        s += __shfl_xor(s, 2);
        s += __shfl_xor(s, 4);
        s += __shfl_xor(s, 8);
        S[j] = s;
    }
    if (l15 == 0) {
        sredS[w][g * 4 + 0] = S[0];
        sredS[w][g * 4 + 1] = S[1];
        sredS[w][g * 4 + 2] = S[2];
        sredS[w][g * 4 + 3] = S[3];
    }
    __syncthreads();
    float inv[4];
#pragma unroll
    for (int j = 0; j < 4; ++j) {
        int r = g * 4 + j;
        inv[j] = 1.0f / (sredS[0][r] + sredS[1][r] + sredS[2][r] + sredS[3][r]);
    }

    // ---- write P: fp32 -> d_out, bf16 -> LDS (swizzled) ----
    float* ab = attn + (long)z * 4194304 + (long)m0 * 2048;
#pragma unroll
    for (int c = 0; c < 8; c++)
#pragma unroll
        for (int t = 0; t < 4; t++) {
            const int col = c * 256 + w * 64 + t * 16 + l15;
#pragma unroll
            for (int j = 0; j < 4; ++j) {
                const int r = g * 4 + j;
                float p = acc[c][t][j] * inv[j];
                ab[(long)r * 2048 + col] = p;
                *(unsigned short*)(smem + r * 4096 + ((col * 2) ^ ((r & 7) << 4))) = f2b(p);
            }
        }
    __syncthreads();

    // ---- PV: out[16][16] per wave, V^T direct from L2 ----
    f32x4 o0 = (f32x4)(0.0f), o1 = (f32x4)(0.0f);
    f32x4 o2 = (f32x4)(0.0f), o3 = (f32x4)(0.0f);
    const char* vtile = vz + (long)(w * 16 + l15) * 4096;
    const char* prow = smem + l15 * 4096;
    const int psw = (l15 & 7) << 4;
#pragma unroll 4
    for (int ks = 0; ks < 64; ks += 4) {
        bf16v pa0 = *(const bf16v*)(prow + (((ks + 0) * 64 + g * 16) ^ psw));
        bf16v pa1 = *(const bf16v*)(prow + (((ks + 1) * 64 + g * 16) ^ psw));
        bf16v pa2 = *(const bf16v*)(prow + (((ks + 2) * 64 + g * 16) ^ psw));
        bf16v pa3 = *(const bf16v*)(prow + (((ks + 3) * 64 + g * 16) ^ psw));
        bf16v bv0 = *(const bf16v*)(vtile + (ks + 0) * 64 + g * 16);
        bf16v bv1 = *(const bf16v*)(vtile + (ks + 1) * 64 + g * 16);
        bf16v bv2 = *(const bf16v*)(vtile + (ks + 2) * 64 + g * 16);
        bf16v bv3 = *(const bf16v*)(vtile + (ks + 3) * 64 + g * 16);
        o0 = __builtin_amdgcn_mfma_f32_16x16x32_bf16(pa0, bv0, o0, 0, 0, 0);
        o1 = __builtin_amdgcn_mfma_f32_16x16x32_bf16(pa1, bv1, o1, 0, 0, 0);
        o2 = __builtin_amdgcn_mfma_f32_16x16x32_bf16(pa2, bv2, o2, 0, 0, 0);
        o3 = __builtin_amdgcn_mfma_f32_16x16x32_bf16(pa3, bv3, o3, 0, 0, 0);
    }
    o0 = o0 + o1 + o2 + o3;

    const int b = z >> 4, h = z & 15;
    const long tokbase = (long)b * 2048 + m0 + g * 4;
#pragma unroll
    for (int j = 0; j < 4; ++j)
        ao[(tokbase + j) * 1024 + h * 64 + w * 16 + l15] = f2b(o0[j]);
}

// ---------------- GEMM modes / args ----------------

enum { M_QKV3 = 0, M_RES = 1, M_RESB = 2, M_RELU = 3 };

struct GArgs {
    const unsigned short* A;
    long lda;
    const unsigned short* B;
    long ldb;
    const float* bias;
    const float* resid;            // fp32 residual (M_RES)
    const unsigned short* residB;  // bf16 residual (M_RESB)
    float* outF;
    unsigned short* outB;    // q (QKV3) / bf16 out
    unsigned short* outB2;   // k (QKV3)
    unsigned short* outB3;   // vt (QKV3)
    long ldo;
    int K;
};

// ---------------- 256x256 counted-vmcnt pipelined GEMM (8 waves) ----------------
template <int MODE>
__global__ __launch_bounds__(512, 1) void gemm256(GArgs g) {
    __shared__ __align__(16) char smem[131072];
    const int tid = threadIdx.x, lane = tid & 63, wave = tid >> 6;
    const int wr = wave >> 2, wc = wave & 3;
    const int g2 = lane >> 4, l15 = lane & 15;
    const long m0 = (long)blockIdx.x * 256, n0 = (long)blockIdx.y * 256;
    const char* Ab = (const char*)(g.A + m0 * g.lda);
    const char* Bb = (const char*)(g.B + n0 * g.ldb);
    const long lda2 = g.lda * 2, ldb2 = g.ldb * 2;

    f32x4 acc[8][4];
#pragma unroll
    for (int mi = 0; mi < 8; mi++)
#pragma unroll
        for (int ni = 0; ni < 4; ni++) acc[mi][ni] = (f32x4)(0.0f);

    auto stage = [&](int t) {
        const int buf = (t & 1) * 32768;
        const long k0b = (long)t * 128;
#pragma unroll
        for (int i = 0; i < 4; ++i) {
            int c = i * 8 + wave;
            int p = c * 1024 + lane * 16;
            int row = p >> 7;
            int scb = (p & 127) ^ ((row & 7) << 4);
            gl_lds16(Ab + (long)row * lda2 + k0b + scb, smem + buf + c * 1024);
        }
#pragma unroll
        for (int i = 0; i < 4; ++i) {
            int c = i * 8 + wave;
            int p = c * 1024 + lane * 16;
            int row = p >> 7;
            int scb = (p & 127) ^ ((row & 7) << 4);
            gl_lds16(Bb + (long)row * ldb2 + k0b + scb, smem + 65536 + buf + c * 1024);
        }
    };

    const int NT = g.K >> 6;
    stage(0);
    for (int t = 0; t < NT; ++t) {
        if (t + 1 < NT) {
            stage(t + 1);
            asm volatile("s_waitcnt vmcnt(8)" ::: "memory");
        } else {
            asm volatile("s_waitcnt vmcnt(0)" ::: "memory");
        }
        __builtin_amdgcn_sched_barrier(0);
        __builtin_amdgcn_s_barrier();
        const char* bufA = smem + (t & 1) * 32768;
        const char* bufB = smem + 65536 + (t & 1) * 32768;
        bf16v bfr[4][2];
#pragma unroll
        for (int ni = 0; ni < 4; ++ni) {
            int r = wc * 64 + ni * 16 + l15;
            const char* bp = bufB + r * 128;
            int sw = (r & 7) << 4;
            bfr[ni][0] = *(const bf16v*)(bp + ((g2 * 16) ^ sw));
            bfr[ni][1] = *(const bf16v*)(bp + ((64 + g2 * 16) ^ sw));
        }
#pragma unroll
        for (int q = 0; q < 4; ++q) {
            bf16v af[2][2];
#pragma unroll
            for (int u = 0; u < 2; ++u) {
                int r = wr * 128 + (q * 2 + u) * 16 + l15;
                const char* ap = bufA + r * 128;
                int sw = (r & 7) << 4;
                af[u][0] = *(const bf16v*)(ap + ((g2 * 16) ^ sw));
                af[u][1] = *(const bf16v*)(ap + ((64 + g2 * 16) ^ sw));
            }
            asm volatile("s_waitcnt lgkmcnt(0)" ::: "memory");
            __builtin_amdgcn_sched_barrier(0);
            __builtin_amdgcn_s_setprio(1);
#pragma unroll
            for (int u = 0; u < 2; ++u)
#pragma unroll
                for (int ni = 0; ni < 4; ++ni) {
                    acc[q * 2 + u][ni] = __builtin_amdgcn_mfma_f32_16x16x32_bf16(
                        af[u][0], bfr[ni][0], acc[q * 2 + u][ni], 0, 0, 0);
                    acc[q * 2 + u][ni] = __builtin_amdgcn_mfma_f32_16x16x32_bf16(
                        af[u][1], bfr[ni][1], acc[q * 2 + u][ni], 0, 0, 0);
                }
            __builtin_amdgcn_s_setprio(0);
        }
        __builtin_amdgcn_sched_barrier(0);
        __builtin_amdgcn_s_barrier();
    }

#pragma unroll
    for (int mi = 0; mi < 8; mi++)
#pragma unroll
        for (int ni = 0; ni < 4; ni++) {
#pragma unroll
            for (int j = 0; j < 4; ++j) {
                long r = m0 + wr * 128 + mi * 16 + g2 * 4 + j;
                long c = n0 + wc * 64 + ni * 16 + l15;
                float tv = acc[mi][ni][j] + g.bias[c];
                g.outB[r * g.ldo + c] = f2b(tv > 0.0f ? tv : 0.0f);  // M_RELU only
            }
        }
}

// ---------------- 256x128 counted-vmcnt pipelined GEMM (8 waves, 2-deep) ----------
template <int MODE>
__global__ __launch_bounds__(512, 1) void gemm256x128(GArgs g) {
    __shared__ __align__(16) char smem[98304];
    const int tid = threadIdx.x, lane = tid & 63, wave = tid >> 6;
    const int wr = wave >> 1, wc = wave & 1;
    const int g2 = lane >> 4, l15 = lane & 15;
    const long m0 = (long)blockIdx.x * 256, n0 = (long)blockIdx.y * 128;
    const char* Ab = (const char*)(g.A + m0 * g.lda);
    const char* Bb = (const char*)(g.B + n0 * g.ldb);
    const long lda2 = g.lda * 2, ldb2 = g.ldb * 2;

    f32x4 acc[4][4];
#pragma unroll
    for (int mi = 0; mi < 4; mi++)
#pragma unroll
        for (int ni = 0; ni < 4; ni++) acc[mi][ni] = (f32x4)(0.0f);

    auto stage = [&](int t) {
        const int bufA = (t & 1) * 32768;
        const int bufB = 65536 + (t & 1) * 16384;
        const long k0b = (long)t * 128;
#pragma unroll
        for (int i = 0; i < 4; ++i) {
            int c = i * 8 + wave;
            int p = c * 1024 + lane * 16;
            int row = p >> 7;
            int scb = (p & 127) ^ ((row & 7) << 4);
            gl_lds16(Ab + (long)row * lda2 + k0b + scb, smem + bufA + c * 1024);
        }
#pragma unroll
        for (int i = 0; i < 2; ++i) {
            int c = i * 8 + wave;
            int p = c * 1024 + lane * 16;
            int row = p >> 7;
            int scb = (p & 127) ^ ((row & 7) << 4);
            gl_lds16(Bb + (long)row * ldb2 + k0b + scb, smem + bufB + c * 1024);
        }
    };

    const int NT = g.K >> 6;
    stage(0);
    for (int t = 0; t < NT; ++t) {
        if (t + 1 < NT) {
            stage(t + 1);
            asm volatile("s_waitcnt vmcnt(6)" ::: "memory");
        } else {
            asm volatile("s_waitcnt vmcnt(0)" ::: "memory");
        }
        __builtin_amdgcn_sched_barrier(0);
        __builtin_amdgcn_s_barrier();
        const char* bufA = smem + (t & 1) * 32768;
        const char* bufB = smem + 65536 + (t & 1) * 16384;
        bf16v bfr[4][2];
#pragma unroll
        for (int ni = 0; ni < 4; ++ni) {
            int r = wc * 64 + ni * 16 + l15;
            const char* bp = bufB + r * 128;
            int sw = (r & 7) << 4;
            bfr[ni][0] = *(const bf16v*)(bp + ((g2 * 16) ^ sw));
            bfr[ni][1] = *(const bf16v*)(bp + ((64 + g2 * 16) ^ sw));
        }
#pragma unroll
        for (int q = 0; q < 4; ++q) {
            bf16v af0, af1;
            {
                int r = wr * 64 + q * 16 + l15;
                const char* ap = bufA + r * 128;
                int sw = (r & 7) << 4;
                af0 = *(const bf16v*)(ap + ((g2 * 16) ^ sw));
                af1 = *(const bf16v*)(ap + ((64 + g2 * 16) ^ sw));
            }
            asm volatile("s_waitcnt lgkmcnt(0)" ::: "memory");
            __builtin_amdgcn_sched_barrier(0);
            __builtin_amdgcn_s_setprio(1);
#pragma unroll
            for (int ni = 0; ni < 4; ++ni) {
                acc[q][ni] = __builtin_amdgcn_mfma_f32_16x16x32_bf16(
                    af0, bfr[ni][0], acc[q][ni], 0, 0, 0);
                acc[q][ni] = __builtin_amdgcn_mfma_f32_16x16x32_bf16(
                    af1, bfr[ni][1], acc[q][ni], 0, 0, 0);
            }
            __builtin_amdgcn_s_setprio(0);
        }
        __builtin_amdgcn_sched_barrier(0);
        __builtin_amdgcn_s_barrier();
    }

    // epilogue: C/D layout col=lane&15, row=(lane>>4)*4+j
#pragma unroll
    for (int mi = 0; mi < 4; mi++)
#pragma unroll
        for (int ni = 0; ni < 4; ni++) {
            if constexpr (MODE == M_QKV3) {
                long r = m0 + wr * 64 + mi * 16 + g2 * 4;
                long c = n0 + wc * 64 + ni * 16 + l15;
                long b = r >> 11, s = r & 2047;
                float bi = g.bias[c];
                if (c < 2048) {
                    unsigned short* dst = (c < 1024) ? g.outB : g.outB2;
                    long h = (c >> 6) & 15, d = c & 63;
                    long base = ((b * 16 + h) * 2048 + s) * 64 + d;
#pragma unroll
                    for (int j = 0; j < 4; ++j)
                        dst[base + (long)j * 64] = f2b(acc[mi][ni][j] + bi);
                } else {
                    long h = (c - 2048) >> 6, d = c & 63;
                    u16x4 u;
#pragma unroll
                    for (int j = 0; j < 4; ++j) u[j] = f2b(acc[mi][ni][j] + bi);
                    *(u16x4*)(g.outB3 + (b * 16 + h) * 131072 + d * 2048 + s) = u;
                }
            } else {
#pragma unroll
                for (int j = 0; j < 4; ++j) {
                    long r = m0 + wr * 64 + mi * 16 + g2 * 4 + j;
                    long c = n0 + wc * 64 + ni * 16 + l15;
                    float v = acc[mi][ni][j] + g.bias[c];
                    long i = r * g.ldo + c;
                    if constexpr (MODE == M_RES) {
                        g.outF[i] = v + g.resid[i];
                    } else {  // M_RESB
                        g.outF[i] = v + b2f(g.residB[i]);
                    }
                }
            }
        }
}

// ---------------- host ----------------

extern "C" void kernel_launch(void* const* d_in, const int* in_sizes, int n_in,
                              void* d_out, int out_size, void* d_ws, size_t ws_size,
                              hipStream_t stream) {
    const float* x = (const float*)d_in[0];
    const float* wq = (const float*)d_in[1];
    const float* bq = (const float*)d_in[2];
    const float* wk = (const float*)d_in[3];
    const float* bk = (const float*)d_in[4];
    const float* wv = (const float*)d_in[5];
    const float* bv = (const float*)d_in[6];
    const float* wo = (const float*)d_in[7];
    const float* bo = (const float*)d_in[8];
    const float* g1 = (const float*)d_in[9];
    const float* b1 = (const float*)d_in[10];
    const float* w1 = (const float*)d_in[11];
    const float* bf1 = (const float*)d_in[12];
    const float* w2 = (const float*)d_in[13];
    const float* bf2 = (const float*)d_in[14];
    const float* g2 = (const float*)d_in[15];
    const float* b2 = (const float*)d_in[16];

    float* out2 = (float*)d_out;
    float* attn = (float*)d_out + 8388608;

    char* ws = (char*)d_ws;
    size_t off = 0;
    auto alc = [&](size_t bytes) { size_t r = off; off += (bytes + 255) & ~(size_t)255; return r; };

    unsigned short* xb    = (unsigned short*)(ws + alc(16777216));
    unsigned short* wqkvT = (unsigned short*)(ws + alc(6291456));   // [3072][1024]
    unsigned short* woT   = (unsigned short*)(ws + alc(2097152));
    unsigned short* w1T   = (unsigned short*)(ws + alc(8388608));
    unsigned short* w2T   = (unsigned short*)(ws + alc(8388608));
    float* bqkv           = (float*)(ws + alc(12288));
    size_t bigOff = alc(67108864);           // q,k,vt block; later reused by ff1
    unsigned short* qb = (unsigned short*)(ws + bigOff);
    unsigned short* kb = qb + 8388608;
    unsigned short* vt = kb + 8388608;
    unsigned short* ff1 = qb;                // alias (q/k/vt dead by FFN1)
    size_t aoOff = alc(16777216);            // attn_out bf16; later out1 bf16
    unsigned short* ao  = (unsigned short*)(ws + aoOff);
    unsigned short* o1b = ao;                // alias
    size_t rOff = alc(33554432);             // resid1; later resid2
    float* r1 = (float*)(ws + rOff);
    float* r2 = r1;                          // alias

    // 1. fused preprocessing: x->bf16, all weight transposes, bias pack
    prep_all<<<20492, 256, 0, stream>>>(x, wq, wk, wv, wo, w1, w2, bq, bk, bv,
                                        xb, wqkvT, woT, w1T, w2T, bqkv);

    // 2. fused QKV (256x128 2-deep, grid 768 = 3.0 waves): Q,K -> [b,h,s,d]; V -> V^T
    {
        GArgs a{};
        a.A = xb; a.lda = 1024; a.B = wqkvT; a.ldb = 1024; a.K = 1024;
        a.bias = bqkv; a.outB = qb; a.outB2 = kb; a.outB3 = vt;
        gemm256x128<M_QKV3><<<dim3(32, 24), 512, 0, stream>>>(a);
    }
    // 3. fused scores+softmax+PV: writes attn (d_out) + ao
    attn_fused<<<8192, 256, 0, stream>>>(qb, kb, vt, attn, ao);
    // 4. out-proj + bias + residual(x) -> r1 fp32 (256x128 2-deep)
    {
        GArgs a{};
        a.A = ao; a.lda = 1024; a.B = woT; a.ldb = 1024;
        a.bias = bo; a.resid = x; a.outF = r1; a.ldo = 1024; a.K = 1024;
        gemm256x128<M_RES><<<dim3(32, 8), 512, 0, stream>>>(a);
    }
    // 5. LN1 -> o1b bf16 only
    ln_rows<<<8192, 256, 0, stream>>>(r1, g1, b1, nullptr, o1b);
    // 6. FFN1 + ReLU (256x256 pipelined, grid 512 = 2.0 waves) -> ff1 bf16
    {
        GArgs a{};
        a.A = o1b; a.lda = 1024; a.B = w1T; a.ldb = 1024;
        a.bias = bf1; a.outB = ff1; a.ldo = 4096; a.K = 1024;
        gemm256<M_RELU><<<dim3(32, 16), 512, 0, stream>>>(a);
    }
    // 7. FFN2 + bias + residual(o1b bf16) -> r2 fp32 (256x128 2-deep, K=4096)
    {
        GArgs a{};
        a.A = ff1; a.lda = 4096; a.B = w2T; a.ldb = 4096;
        a.bias = bf2; a.residB = o1b; a.outF = r2; a.ldo = 1024; a.K = 4096;
        gemm256x128<M_RESB><<<dim3(32, 8), 512, 0, stream>>>(a);
    }
    // 8. LN2 -> out2 (d_out)
    ln_rows<<<8192, 256, 0, stream>>>(r2, g2, b2, out2, nullptr);

    (void)in_sizes; (void)n_in; (void)out_size; (void)ws_size;
}